// Round 3
// baseline (170.348 us; speedup 1.0000x reference)
//
#include <hip/hip_runtime.h>
#include <hip/hip_bf16.h>

#define NHEAD 16
#define HDIM 64
#define DINNER 1024
#define NBATCH 4
#define SEQ 2048
#define NTOK (NBATCH*SEQ)   // 8192

typedef __bf16 bf16;
typedef __bf16 bf16x2 __attribute__((ext_vector_type(2)));
typedef __bf16 bf16x4 __attribute__((ext_vector_type(4)));
typedef __bf16 bf16x8 __attribute__((ext_vector_type(8)));
typedef float f32x4 __attribute__((ext_vector_type(4)));
typedef float f32x16 __attribute__((ext_vector_type(16)));
typedef unsigned int u32;
typedef unsigned int u32x2 __attribute__((ext_vector_type(2)));
typedef unsigned int u32x4 __attribute__((ext_vector_type(4)));

// workspace layout (bf16 element offsets)
#define OFF_BO   8
#define OFF_XB   128
#define OFF_WQT  (OFF_XB + NTOK*HDIM)
#define OFF_WKT  (OFF_WQT + DINNER*HDIM)
#define OFF_WVT  (OFF_WKT + DINNER*HDIM)
#define OFF_WOT  (OFF_WVT + DINNER*HDIM)
#define OFF_Q    (OFF_WOT + DINNER*HDIM)
#define OFF_K    (OFF_Q + NTOK*DINNER)
#define OFF_VT   (OFF_K + NTOK*DINNER)
#define OFF_ATT  (OFF_VT + NTOK*DINNER)            // partial buffer 0 (bf16)
#define OFF_ATT2 (OFF_ATT + NTOK*DINNER)           // partial buffer 1 (bf16)
#define OFF_L    (OFF_ATT2 + NTOK*DINNER)          // l partials: 2 x NTOK*NHEAD floats

// SSCALE folded into Wq: scores arrive as s/8*log2(e) -> P = exp2(st) directly
// (fixed-offset softmax, offset 0 cancels in O/l). Mask -> st=-200 -> exp2=0.
// Fixed-offset softmax makes split-K combination purely ADDITIVE.
#define SSCALE 0.18033688011112042f

static __device__ __forceinline__ bf16x8 ld8(const bf16* p) {
  return *reinterpret_cast<const bf16x8*>(p);
}

// pack two f32 -> one u32 of 2 bf16 (compiler emits v_cvt_pk_bf16_f32)
static __device__ __forceinline__ u32 pkbf(float a, float b) {
  bf16x2 t; t[0] = (bf16)a; t[1] = (bf16)b;
  return __builtin_bit_cast(u32, t);
}

static __device__ __forceinline__ int detect_isbf(const void* x, int tid,
                                                  int* sflag) {
  if (tid < 64) {
    const unsigned short* xb = (const unsigned short*)x;
    bool ok = true;
#pragma unroll
    for (int i = 0; i < 8; i++) {
      unsigned e = (xb[tid * 8 + i] >> 7) & 0xFF;
      ok = ok && (e >= 64 && e <= 140);
    }
    unsigned long long mball = __ballot(ok);
    if (tid == 0) *sflag = (mball == ~0ull) ? 1 : 0;
  }
  __syncthreads();
  return *sflag;
}

// ---------------- kernel 1: normalize inputs into ws (bf16) ----------------
__global__ __launch_bounds__(256) void prep_kernel(
    const void* __restrict__ x, const void* __restrict__ Wq,
    const void* __restrict__ Wk, const void* __restrict__ Wv,
    const void* __restrict__ Wo, const void* __restrict__ bo,
    bf16* __restrict__ ws) {
  __shared__ int sflag;
  int isbf = detect_isbf(x, threadIdx.x, &sflag);
  int z = blockIdx.y;
  int idx = blockIdx.x * 256 + threadIdx.x;
  if (z < 3) {
    const void* src = (z == 0) ? Wq : (z == 1) ? Wk : Wv;
    bf16* dst = ws + ((z == 0) ? OFF_WQT : (z == 1) ? OFF_WKT : OFF_WVT);
    int d = idx >> 10, n = idx & 1023;     // read src[idx] coalesced
    float v = isbf ? (float)((const bf16*)src)[idx] : ((const float*)src)[idx];
    if (z == 0) v *= SSCALE;
    dst[n * HDIM + d] = (bf16)v;
  } else if (z == 3) {
    int k = idx >> 6, n = idx & 63;        // read Wo[idx] coalesced
    float v = isbf ? (float)((const bf16*)Wo)[idx] : ((const float*)Wo)[idx];
    ws[OFF_WOT + n * DINNER + k] = (bf16)v;
  } else if (z == 4) {
    int i = idx * 8;
    bf16x8 v;
    if (isbf) {
      v = ld8((const bf16*)x + i);
    } else {
      f32x4 a = *reinterpret_cast<const f32x4*>((const float*)x + i);
      f32x4 b2 = *reinterpret_cast<const f32x4*>((const float*)x + i + 4);
#pragma unroll
      for (int j = 0; j < 4; j++) { v[j] = (bf16)a[j]; v[4 + j] = (bf16)b2[j]; }
    }
    *reinterpret_cast<bf16x8*>(&ws[OFF_XB + i]) = v;
  } else {
    if (idx < 64) ws[OFF_BO + idx] = isbf ? ((const bf16*)bo)[idx] : (bf16)((const float*)bo)[idx];
  }
}

// ---------------- kernel 2: fused QKV projection + Wo-fold -----------------
__global__ __launch_bounds__(256) void qkv_kernel(bf16* __restrict__ ws) {
  __shared__ __align__(16) bf16 Vst[4][16 * 72];  // per-wave stage, 9.2 KB
  int tt = blockIdx.x, pz = blockIdx.z;
  int w = threadIdx.x >> 6;
  int nc = blockIdx.y * 4 + w;
  int lane = threadIdx.x & 63;
  int lq = lane & 15, quad = lane >> 4;
  const bf16* WT = ws + OFF_WQT + pz * (DINNER * HDIM);
  int n0 = nc * 64;
  bf16x8 w0[4], w1[4];
#pragma unroll
  for (int c = 0; c < 4; c++) {
    const bf16* wr = WT + (n0 + c * 16 + lq) * HDIM;
    w0[c] = ld8(wr + quad * 8);
    w1[c] = ld8(wr + 32 + quad * 8);
  }
  bf16* Qb = ws + OFF_Q;
  bf16* Kb = ws + OFF_K;
  bf16* VTb = ws + OFF_VT;
  bf16x8 ao0[4], ao1[4];
  if (pz == 2) {
    const bf16* WoT = ws + OFF_WOT;
#pragma unroll
    for (int c = 0; c < 4; c++) {
      const bf16* orow = WoT + (size_t)(c * 16 + lq) * DINNER + nc * 64;
      ao0[c] = ld8(orow + quad * 8);
      ao1[c] = ld8(orow + 32 + quad * 8);
    }
  }
#pragma unroll
  for (int mi = 0; mi < 4; mi++) {
    int t0 = tt * 64 + mi * 16;
    const bf16* xrow = ws + OFF_XB + (t0 + lq) * HDIM;
    bf16x8 x0 = ld8(xrow + quad * 8);
    bf16x8 x1 = ld8(xrow + 32 + quad * 8);
    int b = t0 >> 11, s0 = t0 & (SEQ - 1);
    if (pz < 2) {
#pragma unroll
      for (int c = 0; c < 4; c++) {
        f32x4 z = {0.f, 0.f, 0.f, 0.f};
        z = __builtin_amdgcn_mfma_f32_16x16x32_bf16(w0[c], x0, z, 0, 0, 0);
        z = __builtin_amdgcn_mfma_f32_16x16x32_bf16(w1[c], x1, z, 0, 0, 0);
        bf16x4 pk = {(bf16)z[0], (bf16)z[1], (bf16)z[2], (bf16)z[3]};
        bf16* P = (pz == 0) ? Qb : Kb;
        *reinterpret_cast<bf16x4*>(
            &P[((size_t)(b * NHEAD + nc) * SEQ + s0 + lq) * HDIM + c * 16 + quad * 4]) = pk;
      }
    } else {
#pragma unroll
      for (int c = 0; c < 4; c++) {
        f32x4 z = {0.f, 0.f, 0.f, 0.f};
        z = __builtin_amdgcn_mfma_f32_16x16x32_bf16(w0[c], x0, z, 0, 0, 0);
        z = __builtin_amdgcn_mfma_f32_16x16x32_bf16(w1[c], x1, z, 0, 0, 0);
        bf16x4 pk = {(bf16)z[0], (bf16)z[1], (bf16)z[2], (bf16)z[3]};
        *reinterpret_cast<bf16x4*>(&Vst[w][lq * 72 + c * 16 + quad * 4]) = pk;
      }
      bf16x8 bv0 = ld8(&Vst[w][lq * 72 + quad * 8]);
      bf16x8 bv1 = ld8(&Vst[w][lq * 72 + 32 + quad * 8]);
#pragma unroll
      for (int c = 0; c < 4; c++) {
        f32x4 z2 = {0.f, 0.f, 0.f, 0.f};
        z2 = __builtin_amdgcn_mfma_f32_16x16x32_bf16(ao0[c], bv0, z2, 0, 0, 0);
        z2 = __builtin_amdgcn_mfma_f32_16x16x32_bf16(ao1[c], bv1, z2, 0, 0, 0);
#pragma unroll
        for (int r = 0; r < 4; r++) {
          int d = c * 16 + quad * 4 + r;
          VTb[(((size_t)b * NHEAD + nc) * HDIM + d) * SEQ + s0 + lq] = (bf16)z2[r];
        }
      }
    }
  }
}

// ---------------- kernel 3: flash attention (32x32 swapped QK, in-reg P) ----
// m214-style datapath: QK^T computed as mfma(K, Q) at 32x32x16 so each lane
// holds P[k][q=lane&31] (16 k per half-wave). Softmax fully in registers:
// exp2 -> cvt_pk bf16 pairs -> permlane32_swap builds the PV B-fragments
// directly (guide T12 recipe: swap(low_pack, high_pack) -> {w0, w2}).
// No Pl LDS buffer: -12 DS ops/iter, -8KB/iter LDS traffic, -2 LDS latencies
// off the critical path; LDS 40->32 KB.
// Split-K halves + causal pairing (qt=z with 15-z) as round 2: every block
// runs exactly 17 iterations (32 non-causal); partials combine additively.
__global__ __launch_bounds__(256, 2) void flash_kernel(const int* __restrict__ cmask,
                                                       bf16* __restrict__ ws) {
  __shared__ __align__(16) bf16 Kl[2][64 * 64];   // 16 KB, rows=key, cols=d
  __shared__ __align__(16) bf16 Vl[2][64 * 64];   // 16 KB, rows=dout, cols=key
  int bid = blockIdx.x;
  int bh = (bid & 7) * 8 + ((bid >> 3) & 7);      // XCD swizzle: 8 bh/XCD
  int z = (bid >> 6) & 7;
  int half = bid >> 9;
  int w = threadIdx.x >> 6;
  int lane = threadIdx.x & 63;
  int ql = lane & 31, lh = lane >> 5, l7 = lane & 7;
  int causal = cmask[0];
  const bf16* Q = ws + OFF_Q + (size_t)bh * SEQ * HDIM;
  const bf16* K = ws + OFF_K + (size_t)bh * SEQ * HDIM;
  const bf16* VT = ws + OFF_VT + (size_t)bh * HDIM * SEQ;
  int b = bh >> 4, h = bh & 15;
  bf16* ar = ws + OFF_ATT + (size_t)half * NTOK * DINNER;
  float* Lp = reinterpret_cast<float*>(ws + OFF_L) + (size_t)half * NTOK * NHEAD;
  int sr = threadIdx.x >> 2;
  int sg = (threadIdx.x & 3) * 16;
  int sc0 = (((threadIdx.x & 3) * 2) ^ (sr & 7)) << 3;
  int sc1 = (((threadIdx.x & 3) * 2 + 1) ^ (sr & 7)) << 3;

  int bufc = 0;

  for (int seg = 0; seg < 2; ++seg) {
    int qt = seg ? (15 - z) : z;
    int Ts = causal ? (seg ? (32 - 2 * z) : (2 * z + 2)) : 32;
    int hs = Ts >> 1;                 // half-segment length (>=1 always)
    int t0 = half * hs, t1 = t0 + hs;
    int qb = qt * 128;
    int qw = qb + w * 32;
    int qa = qw + ql;                 // this lane's absolute query row

    // Q B-fragments: lane holds Q[qa][d = dsub*16 + lh*8 + j]
    bf16x8 bq[4];
#pragma unroll
    for (int dsub = 0; dsub < 4; dsub++)
      bq[dsub] = ld8(Q + (size_t)qa * HDIM + dsub * 16 + lh * 8);

    f32x16 o0, o1;                    // O^T accum: d 0-31 / 32-63, col=q
#pragma unroll
    for (int r = 0; r < 16; r++) { o0[r] = 0.f; o1[r] = 0.f; }
    float lsum = 0.f;

    bf16x8 kst0 = ld8(K + (size_t)(t0 * 64 + sr) * HDIM + sg);
    bf16x8 kst1 = ld8(K + (size_t)(t0 * 64 + sr) * HDIM + sg + 8);
    bf16x8 vst0 = ld8(VT + (size_t)sr * SEQ + t0 * 64 + sg);
    bf16x8 vst1 = ld8(VT + (size_t)sr * SEQ + t0 * 64 + sg + 8);

    for (int ti = t0; ti < t1; ++ti, ++bufc) {
      int buf = bufc & 1;
      int k0 = ti * 64;
      *reinterpret_cast<bf16x8*>(&Kl[buf][sr * 64 + sc0]) = kst0;
      *reinterpret_cast<bf16x8*>(&Kl[buf][sr * 64 + sc1]) = kst1;
      *reinterpret_cast<bf16x8*>(&Vl[buf][sr * 64 + sc0]) = vst0;
      *reinterpret_cast<bf16x8*>(&Vl[buf][sr * 64 + sc1]) = vst1;
      int kn = (ti + 1 < t1) ? (k0 + 64) : k0;
      kst0 = ld8(K + (size_t)(kn + sr) * HDIM + sg);
      kst1 = ld8(K + (size_t)(kn + sr) * HDIM + sg + 8);
      vst0 = ld8(VT + (size_t)sr * SEQ + kn + sg);
      vst1 = ld8(VT + (size_t)sr * SEQ + kn + sg + 8);
      __syncthreads();
      // wave-level skip: tile fully masked for this wave (no barrier inside)
      if (causal && k0 > qw + 31) continue;

      // QK^T swapped: st[kt] = K[k0+kt*32..+32) x Q^T -> D[k][q=lane&31]
      f32x16 s0, s1;
#pragma unroll
      for (int r = 0; r < 16; r++) { s0[r] = 0.f; s1[r] = 0.f; }
      __builtin_amdgcn_s_setprio(1);
#pragma unroll
      for (int dsub = 0; dsub < 4; dsub++) {
        int co = ((dsub * 2 + lh) ^ l7) << 3;
        bf16x8 a0 = ld8(&Kl[buf][ql * 64 + co]);
        bf16x8 a1 = ld8(&Kl[buf][(32 + ql) * 64 + co]);
        s0 = __builtin_amdgcn_mfma_f32_32x32x16_bf16(a0, bq[dsub], s0, 0, 0, 0);
        s1 = __builtin_amdgcn_mfma_f32_32x32x16_bf16(a1, bq[dsub], s1, 0, 0, 0);
      }
      __builtin_amdgcn_s_setprio(0);

      // causal mask: k(reg r) = k0 + kt*32 + (r&3) + 8*(r>>2) + 4*lh
      if (causal && (k0 + 63 > qw)) {
#pragma unroll
        for (int r = 0; r < 16; r++) {
          int kk = k0 + (r & 3) + 8 * (r >> 2) + 4 * lh;
          if (kk > qa) s0[r] = -200.0f;
          if (kk + 32 > qa) s1[r] = -200.0f;
        }
      }

      // softmax numerator in-register: exp2 -> pack pairs -> permlane32_swap
      // builds B-frags pf[ks]: lane holds P[k = ks*16 + lh*8 + j][q].
      bf16x8 pf[4];
      {
        float e[16];
#pragma unroll
        for (int r = 0; r < 16; r++) { e[r] = exp2f(s0[r]); lsum += e[r]; }
#pragma unroll
        for (int j = 0; j < 2; j++) {
          u32 x0 = pkbf(e[8 * j + 0], e[8 * j + 1]);
          u32 x1 = pkbf(e[8 * j + 2], e[8 * j + 3]);
          u32 y0 = pkbf(e[8 * j + 4], e[8 * j + 5]);
          u32 y1 = pkbf(e[8 * j + 6], e[8 * j + 7]);
          u32x2 r0 = __builtin_amdgcn_permlane32_swap(x0, y0, false, false);
          u32x2 r1 = __builtin_amdgcn_permlane32_swap(x1, y1, false, false);
          u32x4 fw = {r0[0], r1[0], r0[1], r1[1]};
          pf[j] = __builtin_bit_cast(bf16x8, fw);
        }
      }
      {
        float e[16];
#pragma unroll
        for (int r = 0; r < 16; r++) { e[r] = exp2f(s1[r]); lsum += e[r]; }
#pragma unroll
        for (int j = 0; j < 2; j++) {
          u32 x0 = pkbf(e[8 * j + 0], e[8 * j + 1]);
          u32 x1 = pkbf(e[8 * j + 2], e[8 * j + 3]);
          u32 y0 = pkbf(e[8 * j + 4], e[8 * j + 5]);
          u32 y1 = pkbf(e[8 * j + 6], e[8 * j + 7]);
          u32x2 r0 = __builtin_amdgcn_permlane32_swap(x0, y0, false, false);
          u32x2 r1 = __builtin_amdgcn_permlane32_swap(x1, y1, false, false);
          u32x4 fw = {r0[0], r1[0], r0[1], r1[1]};
          pf[2 + j] = __builtin_bit_cast(bf16x8, fw);
        }
      }

      // PV: O[d][q] += V^T[d][k] P[k][q]; A = V^T rows d from Vl
      __builtin_amdgcn_s_setprio(1);
#pragma unroll
      for (int ks = 0; ks < 4; ks++) {
        int co = ((ks * 2 + lh) ^ l7) << 3;
        bf16x8 av0 = ld8(&Vl[buf][ql * 64 + co]);
        bf16x8 av1 = ld8(&Vl[buf][(32 + ql) * 64 + co]);
        o0 = __builtin_amdgcn_mfma_f32_32x32x16_bf16(av0, pf[ks], o0, 0, 0, 0);
        o1 = __builtin_amdgcn_mfma_f32_32x32x16_bf16(av1, pf[ks], o1, 0, 0, 0);
      }
      __builtin_amdgcn_s_setprio(0);
    }

    // epilogue: UNNORMALIZED partial O (bf16) + l partial (f32), buffer[half].
    // o reg r: d = dt*32 + (r&3) + 8*(r>>2) + 4*lh, q = qa.
    lsum += __shfl_xor(lsum, 32);
    size_t row = (size_t)(b * SEQ) + qa;
    if (lane < 32) Lp[row * NHEAD + h] = lsum;
    size_t rowoff = row * DINNER + (size_t)h * HDIM;
#pragma unroll
    for (int g = 0; g < 4; g++) {
      bf16x4 ov0 = {(bf16)o0[4 * g], (bf16)o0[4 * g + 1],
                    (bf16)o0[4 * g + 2], (bf16)o0[4 * g + 3]};
      bf16x4 ov1 = {(bf16)o1[4 * g], (bf16)o1[4 * g + 1],
                    (bf16)o1[4 * g + 2], (bf16)o1[4 * g + 3]};
      *reinterpret_cast<bf16x4*>(&ar[rowoff + 8 * g + 4 * lh]) = ov0;
      *reinterpret_cast<bf16x4*>(&ar[rowoff + 32 + 8 * g + 4 * lh]) = ov1;
    }
  }
}

// ---------------- kernel 4: head-sum reduction + bias ----------------------
// out[t][d] = sum_h (A0[t][h*64+d]+A1[t][h*64+d]) / (l0[t][h]+l1[t][h]) + bo[d]
__global__ __launch_bounds__(256) void reduce_kernel(const bf16* __restrict__ ws,
                                                     const void* __restrict__ x,
                                                     void* __restrict__ outp) {
  __shared__ int sflag;
  int isbf = detect_isbf(x, threadIdx.x, &sflag);
  int idx = blockIdx.x * 256 + threadIdx.x;     // 0..524287
  int t = idx >> 6, d = idx & 63;
  const bf16* a0 = ws + OFF_ATT + (size_t)t * DINNER + d;
  const bf16* a1 = a0 + (size_t)NTOK * DINNER;
  const float* l0 = reinterpret_cast<const float*>(ws + OFF_L) + (size_t)t * NHEAD;
  const float* l1 = l0 + (size_t)NTOK * NHEAD;
  float s = (float)ws[OFF_BO + d];
#pragma unroll
  for (int h = 0; h < 16; h++) {
    float inv = 1.0f / (l0[h] + l1[h]);
    s += ((float)a0[h * 64] + (float)a1[h * 64]) * inv;
  }
  if (isbf) ((bf16*)outp)[idx] = (bf16)s;
  else      ((float*)outp)[idx] = s;
}

extern "C" void kernel_launch(void* const* d_in, const int* in_sizes, int n_in,
                              void* d_out, int out_size, void* d_ws, size_t ws_size,
                              hipStream_t stream) {
  const void* x  = d_in[0];
  const void* Wq = d_in[1];
  const void* Wk = d_in[2];
  const void* Wv = d_in[3];
  const void* Wo = d_in[4];
  const void* bo = d_in[5];
  const int* cm  = (const int*)d_in[6];
  bf16* ws = (bf16*)d_ws;

  hipLaunchKernelGGL(prep_kernel, dim3(256, 6), dim3(256), 0, stream,
                     x, Wq, Wk, Wv, Wo, bo, ws);
  hipLaunchKernelGGL(qkv_kernel, dim3(128, 4, 3), dim3(256), 0, stream, ws);
  hipLaunchKernelGGL(flash_kernel, dim3(1024), dim3(256), 0, stream, cm, ws);
  hipLaunchKernelGGL(reduce_kernel, dim3(2048), dim3(256), 0, stream, ws, x, d_out);
}